// Round 1
// baseline (646.509 us; speedup 1.0000x reference)
//
#include <hip/hip_runtime.h>
#include <hip/hip_bf16.h>
#include <cstdint>

// GCN: 2-layer GraphConv + dense head on MI355X. Round 5:
//  - DETERMINISM FIX: bitonic-sort each CSR adjacency segment after atomic fill
//    (atomicAdd fill order varies per graph replay -> fp32 sum order varies ->
//    bf16 rounding flips amplified through layer 2 -> post-timing absmax drift).
//  - merged prep kernels: [count+castx+castw+P1], [exscan x2 + W2a/W2b/bout]
//  - GEMM: dual A/B staged per k-iter (16 iters x 32 MFMA, barriers halved)
//  - agg: 8-edge unroll for MLP
//  - 8 total dispatches (memset + 7 kernels)

static constexpr int N0 = 100000;
static constexpr int N1 = 20000;
static constexpr int N2 = 4000;
static constexpr int HH = 512;
static constexpr int C  = 10;
static constexpr int M1PAD = 20096;  // 157 * 128

using frag  = __attribute__((ext_vector_type(8))) short;
using f32x4 = __attribute__((ext_vector_type(4))) float;

__device__ inline float bf2f(unsigned short u) {
    unsigned t = ((unsigned)u) << 16; float f; __builtin_memcpy(&f, &t, 4); return f;
}
__device__ inline unsigned short f2bf(float f) {
    unsigned u; __builtin_memcpy(&u, &f, 4);
    u += 0x7FFFu + ((u >> 16) & 1u);  // RNE
    return (unsigned short)(u >> 16);
}
__device__ inline void gld16(const void* g, void* l) {
    __builtin_amdgcn_global_load_lds((const __attribute__((address_space(1))) void*)g,
                                     (__attribute__((address_space(3))) void*)l,
                                     16, 0, 0);
}

// ---------------- prep1: edge-count atomics + x cast + weight cast + P1 -----
__global__ __launch_bounds__(256)
void prep1_k(const int* __restrict__ dst1, const int* __restrict__ dst2,
             int* __restrict__ cnt1, int* __restrict__ cnt2, int E1, int E2,
             const float* __restrict__ x, unsigned short* __restrict__ xb,
             const float* __restrict__ Wrel1, const float* __restrict__ Wroot1,
             unsigned short* __restrict__ Wt,
             const float* __restrict__ Wlin, const float* __restrict__ Whead,
             float* __restrict__ P1,
             int nbCount, int nbCast) {
    __shared__ float tsh[32][33];
    int b = blockIdx.x;
    if (b < nbCount) {                       // ---- edge counting (atomics) ----
        int g = b * 256 + threadIdx.x;
        if (g < E1) atomicAdd(&cnt1[dst1[g]], 1);
        else if (g < E1 + E2) atomicAdd(&cnt2[dst2[g - E1]], 1);
        return;
    }
    b -= nbCount;
    if (b < nbCast) {                        // ---- x -> bf16 (8 elem/thr) ----
        int g = b * 256 + threadIdx.x;
        const float4* p = (const float4*)x + (size_t)g * 2;
        float4 a = p[0], bb = p[1];
        unsigned short t[8] = {f2bf(a.x), f2bf(a.y), f2bf(a.z), f2bf(a.w),
                               f2bf(bb.x), f2bf(bb.y), f2bf(bb.z), f2bf(bb.w)};
        *(uint4*)(xb + (size_t)g * 8) = *(const uint4*)t;
        return;
    }
    b -= nbCast;
    if (b < 512) {                           // ---- weight transpose+cast ----
        int z = b >> 8, rem = b & 255;
        int bx = (rem & 15) * 32, by = (rem >> 4) * 32;
        const float* W = z ? Wroot1 : Wrel1;
        unsigned short* O = Wt + (size_t)z * HH * HH;
        int tx = threadIdx.x & 31, ty = threadIdx.x >> 5;
#pragma unroll
        for (int i = 0; i < 4; ++i)
            tsh[ty + i * 8][tx] = W[(size_t)(by + ty + i * 8) * HH + bx + tx];
        __syncthreads();
#pragma unroll
        for (int i = 0; i < 4; ++i)
            O[(size_t)(bx + ty + i * 8) * HH + by + tx] = f2bf(tsh[tx][ty + i * 8]);
        return;
    }
    b -= 512;
    {                                        // ---- P1 = Wlin @ Whead ----
        int g = b * 256 + threadIdx.x;
        if (g < HH * C) {
            int k = g / C, c = g % C;
            float acc = 0.f;
            const float* row = Wlin + (size_t)k * HH;
#pragma unroll 4
            for (int j = 0; j < HH; ++j) acc += row[j] * Whead[j * C + c];
            P1[g] = acc;
        }
    }
}

// ---------------- prep2: two exscans + W2aT/W2bT + bout ----------------
__global__ __launch_bounds__(1024)
void prep2_k(const int* __restrict__ cnt1, int* __restrict__ rs1,
             const int* __restrict__ cnt2, int* __restrict__ rs2,
             const float* __restrict__ Wrel2, const float* __restrict__ Wroot2,
             const float* __restrict__ P1,
             const float* __restrict__ brel2, const float* __restrict__ blin,
             const float* __restrict__ Whead, const float* __restrict__ bhead,
             float* __restrict__ W2aT, float* __restrict__ W2bT,
             float* __restrict__ bout) {
    __shared__ int part[1024];
    int blk = blockIdx.x;
    int t = threadIdx.x;
    if (blk < 2) {                           // ---- exclusive scans ----
        const int* cnt = blk ? cnt2 : cnt1;
        int* rs = blk ? rs2 : rs1;
        int n = blk ? N2 : N1;
        int chunk = (n + 1023) >> 10;
        int bb = t * chunk;
        int e = min(bb + chunk, n);
        int s = 0;
        for (int i = bb; i < e; ++i) s += cnt[i];
        part[t] = s;
        __syncthreads();
        for (int off = 1; off < 1024; off <<= 1) {
            int add = (t >= off) ? part[t - off] : 0;
            __syncthreads();
            part[t] += add;
            __syncthreads();
        }
        int base = (t == 0) ? 0 : part[t - 1];
        for (int i = bb; i < e; ++i) { rs[i] = base; base += cnt[i]; }
        if (t == 1023) rs[n] = part[1023];
        return;
    }
    if (blk < 12) {                          // ---- W2aT / W2bT ----
        int z = (blk - 2) >= 5;
        int g = (blk - 2 - z * 5) * 1024 + t;
        if (g < HH * C) {
            const float* W = z ? Wroot2 : Wrel2;
            float* O = z ? W2bT : W2aT;
            int k = g / C, c = g % C;
            float acc = 0.f;
            const float* row = W + (size_t)k * HH;
#pragma unroll 4
            for (int j = 0; j < HH; ++j) acc += row[j] * P1[j * C + c];
            O[c * HH + k] = acc;             // transposed [10][512]
        }
        return;
    }
    if (t < C) {                             // ---- bout ----
        float acc = bhead[t];
        for (int j = 0; j < HH; ++j)
            acc += brel2[j] * P1[j * C + t] + blin[j] * Whead[j * C + t];
        bout[t] = acc;
    }
}

// ---------------- CSR fill (both layers) ----------------
__global__ void fill_both_k(const int* __restrict__ src1, const int* __restrict__ dst1,
                            const int* __restrict__ src2, const int* __restrict__ dst2,
                            const int* __restrict__ rs1, const int* __restrict__ rs2,
                            int* __restrict__ cur1, int* __restrict__ cur2,
                            int* __restrict__ eidx1, int* __restrict__ eidx2,
                            int E1, int E2) {
    int g = blockIdx.x * 256 + threadIdx.x;
    if (g < E1) {
        int d = dst1[g];
        int pos = atomicAdd(&cur1[d], 1);
        eidx1[rs1[d] + pos] = src1[g];
    } else if (g < E1 + E2) {
        int gg = g - E1;
        int d = dst2[gg];
        int pos = atomicAdd(&cur2[d], 1);
        eidx2[rs2[d] + pos] = src2[gg];
    }
}

// ---------------- canonicalize CSR: sort each segment ascending ----------------
// atomicAdd fill order is nondeterministic per replay; sorted segments are a
// pure function of the inputs -> bit-identical aggregation on every replay.
// One wave per node; 64-lane bitonic via shfl_xor (deg is Poisson(25)).
__global__ __launch_bounds__(256)
void sort_k(const int* __restrict__ rs1, int* __restrict__ eidx1,
            const int* __restrict__ rs2, int* __restrict__ eidx2) {
    int node = blockIdx.x * 4 + (threadIdx.x >> 6);
    const int* rs; int* e;
    if (node < N1) { rs = rs1; e = eidx1; }
    else if (node < N1 + N2) { rs = rs2; e = eidx2; node -= N1; }
    else return;
    int l = threadIdx.x & 63;
    int s = rs[node], t = rs[node + 1];
    int deg = t - s;
    if (deg <= 1) return;
    if (deg <= 64) {
        int v = (l < deg) ? e[s + l] : 0x7FFFFFFF;
#pragma unroll
        for (int k = 2; k <= 64; k <<= 1) {
#pragma unroll
            for (int j = k >> 1; j > 0; j >>= 1) {
                int pv = __shfl_xor(v, j);
                bool lower = (l & j) == 0;
                bool asc = (l & k) == 0;
                int mn = min(v, pv), mx = max(v, pv);
                v = (lower == asc) ? mn : mx;
            }
        }
        if (l < deg) e[s + l] = v;
    } else if (l == 0) {
        // ultra-rare tail (P(deg>64) ~ 1e-10 per node): serial insertion sort
        for (int i = s + 1; i < t; ++i) {
            int v = e[i]; int j = i - 1;
            while (j >= s && e[j] > v) { e[j + 1] = e[j]; --j; }
            e[j + 1] = v;
        }
    }
}

// ---------------- aggregation: one wave per node, 8-edge unroll ----------------
__global__ __launch_bounds__(256)
void agg_bf16_k(const unsigned short* __restrict__ x, const int* __restrict__ rs,
                const int* __restrict__ eidx, unsigned short* __restrict__ out, int n) {
    int node = blockIdx.x * 4 + (threadIdx.x >> 6);
    if (node >= n) return;
    int l = threadIdx.x & 63;
    int s = rs[node], e = rs[node + 1];
    float acc[8] = {};
    int i = s;
    for (; i + 8 <= e; i += 8) {
        uint4 v[8];
#pragma unroll
        for (int u = 0; u < 8; ++u)
            v[u] = *(const uint4*)(x + (size_t)eidx[i + u] * HH + l * 8);
#pragma unroll
        for (int u = 0; u < 8; ++u) {
            const unsigned short* pv = (const unsigned short*)&v[u];
#pragma unroll
            for (int j = 0; j < 8; ++j) acc[j] += bf2f(pv[j]);
        }
    }
    for (; i < e; ++i) {
        uint4 a = *(const uint4*)(x + (size_t)eidx[i] * HH + l * 8);
        const unsigned short* pa = (const unsigned short*)&a;
#pragma unroll
        for (int j = 0; j < 8; ++j) acc[j] += bf2f(pa[j]);
    }
    unsigned short o[8];
#pragma unroll
    for (int j = 0; j < 8; ++j) o[j] = f2bf(acc[j]);
    *(uint4*)(out + (size_t)node * HH + l * 8) = *(const uint4*)o;
}

// ---------------- bf16 MFMA GEMM (layer 1, dual fused in k-loop) ----------------
// h = relu(agg1@Wrel1^T' + x@Wroot1^T' + b); Bt inputs are [N][K] bf16.
__global__ __launch_bounds__(256)
void gemm_mfma_k(const short* __restrict__ A1, const short* __restrict__ B1t,
                 const short* __restrict__ A2, const short* __restrict__ B2t,
                 const float* __restrict__ bias, unsigned short* __restrict__ Cout,
                 int M) {
    __shared__ __align__(16) short Ls[4 * 128 * 32];   // A1 | A2 | B1 | B2 (32 KB)
    short* As1 = Ls;
    short* As2 = Ls + 4096;
    short* Bs1 = Ls + 8192;
    short* Bs2 = Ls + 12288;
    const int bn = blockIdx.x * 128;
    const int bm = blockIdx.y * 128;
    const int tid = threadIdx.x;
    const int lane = tid & 63;
    const int wave = tid >> 6;
    const int l15 = lane & 15;
    const int quad = lane >> 4;
    const int wm = (wave >> 1) * 64;
    const int wn = (wave & 1) * 64;
    const int r0 = tid >> 2;          // 0..63
    const int sg = (tid & 3) * 8;     // bf16 offset in 32-k row

    f32x4 acc[4][4] = {};

    for (int k0 = 0; k0 < 512; k0 += 32) {
        gld16(A1 + (size_t)(bm + r0) * 512 + k0 + sg,        As1 + tid * 8);
        gld16(A1 + (size_t)(bm + r0 + 64) * 512 + k0 + sg,   As1 + (tid + 256) * 8);
        gld16(A2 + (size_t)(bm + r0) * 512 + k0 + sg,        As2 + tid * 8);
        gld16(A2 + (size_t)(bm + r0 + 64) * 512 + k0 + sg,   As2 + (tid + 256) * 8);
        gld16(B1t + (size_t)(bn + r0) * 512 + k0 + sg,       Bs1 + tid * 8);
        gld16(B1t + (size_t)(bn + r0 + 64) * 512 + k0 + sg,  Bs1 + (tid + 256) * 8);
        gld16(B2t + (size_t)(bn + r0) * 512 + k0 + sg,       Bs2 + tid * 8);
        gld16(B2t + (size_t)(bn + r0 + 64) * 512 + k0 + sg,  Bs2 + (tid + 256) * 8);
        __syncthreads();
        {
            frag a[4], b[4];
#pragma unroll
            for (int mi = 0; mi < 4; ++mi)
                a[mi] = *(const frag*)(As1 + (wm + mi * 16 + l15) * 32 + quad * 8);
#pragma unroll
            for (int ni = 0; ni < 4; ++ni)
                b[ni] = *(const frag*)(Bs1 + (wn + ni * 16 + l15) * 32 + quad * 8);
#pragma unroll
            for (int mi = 0; mi < 4; ++mi)
#pragma unroll
                for (int ni = 0; ni < 4; ++ni)
                    acc[mi][ni] = __builtin_amdgcn_mfma_f32_16x16x32_bf16(
                        a[mi], b[ni], acc[mi][ni], 0, 0, 0);
#pragma unroll
            for (int mi = 0; mi < 4; ++mi)
                a[mi] = *(const frag*)(As2 + (wm + mi * 16 + l15) * 32 + quad * 8);
#pragma unroll
            for (int ni = 0; ni < 4; ++ni)
                b[ni] = *(const frag*)(Bs2 + (wn + ni * 16 + l15) * 32 + quad * 8);
#pragma unroll
            for (int mi = 0; mi < 4; ++mi)
#pragma unroll
                for (int ni = 0; ni < 4; ++ni)
                    acc[mi][ni] = __builtin_amdgcn_mfma_f32_16x16x32_bf16(
                        a[mi], b[ni], acc[mi][ni], 0, 0, 0);
        }
        __syncthreads();
    }

#pragma unroll
    for (int ni = 0; ni < 4; ++ni) {
        const int gn = bn + wn + ni * 16 + l15;
        const float bv = bias[gn];
#pragma unroll
        for (int mi = 0; mi < 4; ++mi) {
            const int gm0 = bm + wm + mi * 16 + quad * 4;
#pragma unroll
            for (int r = 0; r < 4; ++r) {
                const int gm = gm0 + r;
                if (gm < M) {
                    float v = fmaxf(acc[mi][ni][r] + bv, 0.f);
                    Cout[(size_t)gm * 512 + gn] = f2bf(v);
                }
            }
        }
    }
}

// ---------------- fused tail: gather + [512,10] matvec -> out ----------------
__global__ __launch_bounds__(256)
void tail_k(const unsigned short* __restrict__ h, const int* __restrict__ rs,
            const int* __restrict__ eidx,
            const float* __restrict__ W2aT, const float* __restrict__ W2bT,
            const float* __restrict__ bout, float* __restrict__ out) {
    int node = blockIdx.x * 4 + (threadIdx.x >> 6);
    if (node >= N2) return;
    int l = threadIdx.x & 63;
    int s = rs[node], e = rs[node + 1];
    float acc[8] = {};
    int i = s;
    for (; i + 4 <= e; i += 4) {
        uint4 v[4];
#pragma unroll
        for (int u = 0; u < 4; ++u)
            v[u] = *(const uint4*)(h + (size_t)eidx[i + u] * HH + l * 8);
#pragma unroll
        for (int u = 0; u < 4; ++u) {
            const unsigned short* pv = (const unsigned short*)&v[u];
#pragma unroll
            for (int j = 0; j < 8; ++j) acc[j] += bf2f(pv[j]);
        }
    }
    for (; i < e; ++i) {
        uint4 a = *(const uint4*)(h + (size_t)eidx[i] * HH + l * 8);
        const unsigned short* pa = (const unsigned short*)&a;
#pragma unroll
        for (int j = 0; j < 8; ++j) acc[j] += bf2f(pa[j]);
    }
    float r[8];
    {
        uint4 a = *(const uint4*)(h + (size_t)node * HH + l * 8);
        const unsigned short* pa = (const unsigned short*)&a;
#pragma unroll
        for (int j = 0; j < 8; ++j) r[j] = bf2f(pa[j]);
    }
    float p[C];
#pragma unroll
    for (int c = 0; c < C; ++c) {
        const float* wa = W2aT + c * HH + l * 8;
        const float* wb = W2bT + c * HH + l * 8;
        float4 wa0 = *(const float4*)wa, wa1 = *(const float4*)(wa + 4);
        float4 wb0 = *(const float4*)wb, wb1 = *(const float4*)(wb + 4);
        float v = acc[0] * wa0.x + acc[1] * wa0.y + acc[2] * wa0.z + acc[3] * wa0.w
                + acc[4] * wa1.x + acc[5] * wa1.y + acc[6] * wa1.z + acc[7] * wa1.w
                + r[0] * wb0.x + r[1] * wb0.y + r[2] * wb0.z + r[3] * wb0.w
                + r[4] * wb1.x + r[5] * wb1.y + r[6] * wb1.z + r[7] * wb1.w;
#pragma unroll
        for (int off = 32; off; off >>= 1) v += __shfl_xor(v, off);
        p[c] = v;
    }
    if (l == 0) {
#pragma unroll
        for (int c = 0; c < C; ++c) out[(size_t)node * C + c] = p[c] + bout[c];
    }
}

extern "C" void kernel_launch(void* const* d_in, const int* in_sizes, int n_in,
                              void* d_out, int out_size, void* d_ws, size_t ws_size,
                              hipStream_t stream) {
    const float* x      = (const float*)d_in[0];
    const int*   src1   = (const int*)d_in[1];
    const int*   dst1   = (const int*)d_in[2];
    const int*   src2   = (const int*)d_in[3];
    const int*   dst2   = (const int*)d_in[4];
    const float* Wrel1  = (const float*)d_in[5];
    const float* brel1  = (const float*)d_in[6];
    const float* Wroot1 = (const float*)d_in[7];
    const float* Wrel2  = (const float*)d_in[8];
    const float* brel2  = (const float*)d_in[9];
    const float* Wroot2 = (const float*)d_in[10];
    const float* Wlin   = (const float*)d_in[11];
    const float* blin   = (const float*)d_in[12];
    const float* Whead  = (const float*)d_in[13];
    const float* bhead  = (const float*)d_in[14];
    float* out = (float*)d_out;

    const int E1 = in_sizes[1];
    const int E2 = in_sizes[3];

    // ---- workspace layout (~147 MB; ws is ~800 MB per fill evidence) ----
    char* w = (char*)d_ws;
    auto alloc = [&](size_t bytes) { char* p = w; w += (bytes + 255) & ~(size_t)255; return p; };
    unsigned short* xb    = (unsigned short*)alloc((size_t)N0 * HH * 2);
    unsigned short* agg1b = (unsigned short*)alloc((size_t)M1PAD * HH * 2);
    unsigned short* hb    = (unsigned short*)alloc((size_t)M1PAD * HH * 2);
    unsigned short* Wt    = (unsigned short*)alloc((size_t)2 * HH * HH * 2);
    float* P1    = (float*)alloc((size_t)HH * C * 4);
    float* W2aT  = (float*)alloc((size_t)HH * C * 4);
    float* W2bT  = (float*)alloc((size_t)HH * C * 4);
    float* boutp = (float*)alloc(256);
    int* ip = (int*)alloc((size_t)(2 * N1 + 2 * N2 + (N1 + 1) + (N2 + 1) + E1 + E2) * 4);
    int* cnt1  = ip;
    int* cur1  = ip + N1;
    int* cnt2  = ip + 2 * N1;
    int* cur2  = ip + 2 * N1 + N2;
    int* rs1   = ip + 2 * N1 + 2 * N2;
    int* rs2   = rs1 + N1 + 1;
    int* eidx1 = rs2 + N2 + 1;
    int* eidx2 = eidx1 + E1;

    const short* Wrel1t  = (const short*)(Wt);
    const short* Wroot1t = (const short*)(Wt + (size_t)HH * HH);

    hipMemsetAsync(ip, 0, (size_t)(2 * N1 + 2 * N2) * sizeof(int), stream);

    // ---- prep1: count + castx + castw + P1 ----
    const int nbCount = (E1 + E2 + 255) / 256;
    const int nbCast  = N0 * HH / 8 / 256;   // 25000
    const int nbP1    = (HH * C + 255) / 256;
    prep1_k<<<nbCount + nbCast + 512 + nbP1, 256, 0, stream>>>(
        dst1, dst2, cnt1, cnt2, E1, E2, x, xb, Wrel1, Wroot1, Wt,
        Wlin, Whead, P1, nbCount, nbCast);

    // ---- prep2: exscans + W2aT/W2bT + bout ----
    prep2_k<<<13, 1024, 0, stream>>>(cnt1, rs1, cnt2, rs2, Wrel2, Wroot2, P1,
                                     brel2, blin, Whead, bhead, W2aT, W2bT, boutp);

    // ---- CSR fill ----
    fill_both_k<<<nbCount, 256, 0, stream>>>(src1, dst1, src2, dst2, rs1, rs2,
                                             cur1, cur2, eidx1, eidx2, E1, E2);

    // ---- canonicalize adjacency order (determinism across replays) ----
    sort_k<<<(N1 + N2 + 3) / 4, 256, 0, stream>>>(rs1, eidx1, rs2, eidx2);

    // ---- layer 1 ----
    agg_bf16_k<<<(N1 + 3) / 4, 256, 0, stream>>>(xb, rs1, eidx1, agg1b, N1);
    {
        dim3 grid(HH / 128, M1PAD / 128);
        gemm_mfma_k<<<grid, 256, 0, stream>>>(
            (const short*)agg1b, Wrel1t, (const short*)xb, Wroot1t, brel1, hb, N1);
    }

    // ---- fused layer 2 + head ----
    tail_k<<<(N2 + 3) / 4, 256, 0, stream>>>(hb, rs2, eidx2, W2aT, W2bT, boutp, out);
}

// Round 2
// 535.306 us; speedup vs baseline: 1.2077x; 1.2077x over previous
//
#include <hip/hip_runtime.h>
#include <hip/hip_bf16.h>
#include <cstdint>

// GCN: 2-layer GraphConv + dense head on MI355X. Round 6:
//  - atomics halved: count pass records posE; fill is atomic-free scatter
//  - prep1 grid reordered: long-pole blocks (P1, transpose) first, cast last
//  - P1 / W2aT / W2bT: operand staged in LDS, float4 row loads, 4 accumulators
//  - bout: 512-thread parallel + shuffle reduce (was 10 threads x 512 serial)
//  - cast widened to 64B read / 32B write per lane
//  - 8 total dispatches (memset + 7 kernels)

static constexpr int N0 = 100000;
static constexpr int N1 = 20000;
static constexpr int N2 = 4000;
static constexpr int HH = 512;
static constexpr int C  = 10;
static constexpr int M1PAD = 20096;  // 157 * 128

using frag  = __attribute__((ext_vector_type(8))) short;
using f32x4 = __attribute__((ext_vector_type(4))) float;

__device__ inline float bf2f(unsigned short u) {
    unsigned t = ((unsigned)u) << 16; float f; __builtin_memcpy(&f, &t, 4); return f;
}
__device__ inline unsigned short f2bf(float f) {
    unsigned u; __builtin_memcpy(&u, &f, 4);
    u += 0x7FFFu + ((u >> 16) & 1u);  // RNE
    return (unsigned short)(u >> 16);
}
__device__ inline void gld16(const void* g, void* l) {
    __builtin_amdgcn_global_load_lds((const __attribute__((address_space(1))) void*)g,
                                     (__attribute__((address_space(3))) void*)l,
                                     16, 0, 0);
}

// ---------------- prep1: P1 + weight cast + edge-count(pos) + x cast -----
__global__ __launch_bounds__(256)
void prep1_k(const int* __restrict__ dst1, const int* __restrict__ dst2,
             int* __restrict__ cnt1, int* __restrict__ cnt2, int* __restrict__ posE,
             int E1, int E2,
             const float* __restrict__ x, unsigned short* __restrict__ xb,
             const float* __restrict__ Wrel1, const float* __restrict__ Wroot1,
             unsigned short* __restrict__ Wt,
             const float* __restrict__ Wlin, const float* __restrict__ Whead,
             float* __restrict__ P1,
             int nbCount) {
    __shared__ float sh[5120];   // 20 KB: Whead tile / transpose tile
    int b = blockIdx.x;
    const int tid = threadIdx.x;
    if (b < 20) {                            // ---- P1 = Wlin @ Whead (first: long pole) ----
        for (int i = tid; i < HH * C; i += 256) sh[i] = Whead[i];
        __syncthreads();
        int g = b * 256 + tid;               // 0..5119
        int k = g / C, c = g % C;
        const float4* rp = (const float4*)(Wlin + (size_t)k * HH);
        float a0 = 0.f, a1 = 0.f, a2 = 0.f, a3 = 0.f;
#pragma unroll 4
        for (int j = 0; j < HH / 4; ++j) {
            float4 v = rp[j];
            int j4 = j * 4;
            a0 += v.x * sh[(j4    ) * C + c];
            a1 += v.y * sh[(j4 + 1) * C + c];
            a2 += v.z * sh[(j4 + 2) * C + c];
            a3 += v.w * sh[(j4 + 3) * C + c];
        }
        P1[g] = (a0 + a1) + (a2 + a3);
        return;
    }
    b -= 20;
    if (b < 512) {                           // ---- weight transpose+cast ----
        int z = b >> 8, rem = b & 255;
        int bx = (rem & 15) * 32, by = (rem >> 4) * 32;
        const float* W = z ? Wroot1 : Wrel1;
        unsigned short* O = Wt + (size_t)z * HH * HH;
        int tx = tid & 31, ty = tid >> 5;
#pragma unroll
        for (int i = 0; i < 4; ++i)
            sh[(ty + i * 8) * 33 + tx] = W[(size_t)(by + ty + i * 8) * HH + bx + tx];
        __syncthreads();
#pragma unroll
        for (int i = 0; i < 4; ++i)
            O[(size_t)(bx + ty + i * 8) * HH + by + tx] = f2bf(sh[tx * 33 + ty + i * 8]);
        return;
    }
    b -= 512;
    if (b < nbCount) {                       // ---- edge counting + position record ----
        int g = b * 256 + tid;
        if (g < E1) posE[g] = atomicAdd(&cnt1[dst1[g]], 1);
        else if (g < E1 + E2) posE[g] = atomicAdd(&cnt2[dst2[g - E1]], 1);
        return;
    }
    b -= nbCount;
    {                                        // ---- x -> bf16 (16 elem/thr, 64B in flight) ----
        int g = b * 256 + tid;
        const float4* p = (const float4*)x + (size_t)g * 4;
        float4 v0 = p[0], v1 = p[1], v2 = p[2], v3 = p[3];
        unsigned short t[16] = {f2bf(v0.x), f2bf(v0.y), f2bf(v0.z), f2bf(v0.w),
                                f2bf(v1.x), f2bf(v1.y), f2bf(v1.z), f2bf(v1.w),
                                f2bf(v2.x), f2bf(v2.y), f2bf(v2.z), f2bf(v2.w),
                                f2bf(v3.x), f2bf(v3.y), f2bf(v3.z), f2bf(v3.w)};
        uint4* o = (uint4*)(xb + (size_t)g * 16);
        o[0] = ((const uint4*)t)[0];
        o[1] = ((const uint4*)t)[1];
    }
}

// ---------------- prep2: two exscans + W2aT/W2bT + bout ----------------
__global__ __launch_bounds__(1024)
void prep2_k(const int* __restrict__ cnt1, int* __restrict__ rs1,
             const int* __restrict__ cnt2, int* __restrict__ rs2,
             const float* __restrict__ Wrel2, const float* __restrict__ Wroot2,
             const float* __restrict__ P1,
             const float* __restrict__ brel2, const float* __restrict__ blin,
             const float* __restrict__ Whead, const float* __restrict__ bhead,
             float* __restrict__ W2aT, float* __restrict__ W2bT,
             float* __restrict__ bout) {
    __shared__ float fsh[5120];              // 20 KB: scan ints / P1 tile / reduce
    int* part = (int*)fsh;
    int blk = blockIdx.x;
    int t = threadIdx.x;
    if (blk < 2) {                           // ---- exclusive scans ----
        const int* cnt = blk ? cnt2 : cnt1;
        int* rs = blk ? rs2 : rs1;
        int n = blk ? N2 : N1;
        int chunk = (n + 1023) >> 10;
        int bb = t * chunk;
        int e = min(bb + chunk, n);
        int s = 0;
        for (int i = bb; i < e; ++i) s += cnt[i];
        part[t] = s;
        __syncthreads();
        for (int off = 1; off < 1024; off <<= 1) {
            int add = (t >= off) ? part[t - off] : 0;
            __syncthreads();
            part[t] += add;
            __syncthreads();
        }
        int base = (t == 0) ? 0 : part[t - 1];
        for (int i = bb; i < e; ++i) { rs[i] = base; base += cnt[i]; }
        if (t == 1023) rs[n] = part[1023];
        return;
    }
    if (blk < 12) {                          // ---- W2aT / W2bT (P1 staged in LDS) ----
        for (int i = t; i < HH * C; i += 1024) fsh[i] = P1[i];
        __syncthreads();
        int z = (blk - 2) >= 5;
        int g = (blk - 2 - z * 5) * 1024 + t;
        if (g < HH * C) {
            const float* W = z ? Wroot2 : Wrel2;
            float* O = z ? W2bT : W2aT;
            int k = g / C, c = g % C;
            const float4* rp = (const float4*)(W + (size_t)k * HH);
            float a0 = 0.f, a1 = 0.f, a2 = 0.f, a3 = 0.f;
#pragma unroll 4
            for (int j = 0; j < HH / 4; ++j) {
                float4 v = rp[j];
                int j4 = j * 4;
                a0 += v.x * fsh[(j4    ) * C + c];
                a1 += v.y * fsh[(j4 + 1) * C + c];
                a2 += v.z * fsh[(j4 + 2) * C + c];
                a3 += v.w * fsh[(j4 + 3) * C + c];
            }
            O[c * HH + k] = (a0 + a1) + (a2 + a3);   // transposed [10][512]
        }
        return;
    }
    {                                        // ---- bout: parallel over j + reduce ----
        float pr[C];
#pragma unroll
        for (int c = 0; c < C; ++c) pr[c] = 0.f;
        if (t < HH) {
            float br = brel2[t], bl = blin[t];
            const float* p1r = P1 + (size_t)t * C;
            const float* whr = Whead + (size_t)t * C;
#pragma unroll
            for (int c = 0; c < C; ++c) pr[c] = br * p1r[c] + bl * whr[c];
        }
#pragma unroll
        for (int c = 0; c < C; ++c)
#pragma unroll
            for (int off = 32; off; off >>= 1) pr[c] += __shfl_xor(pr[c], off);
        int wv = t >> 6, ln = t & 63;
        if (ln == 0)
#pragma unroll
            for (int c = 0; c < C; ++c) fsh[wv * C + c] = pr[c];
        __syncthreads();
        if (t < C) {
            float acc = bhead[t];
#pragma unroll
            for (int w = 0; w < 16; ++w) acc += fsh[w * C + t];
            bout[t] = acc;
        }
    }
}

// ---------------- CSR fill (atomic-free: positions from count pass) ----------------
__global__ void fill_both_k(const int* __restrict__ src1, const int* __restrict__ dst1,
                            const int* __restrict__ src2, const int* __restrict__ dst2,
                            const int* __restrict__ rs1, const int* __restrict__ rs2,
                            const int* __restrict__ posE,
                            int* __restrict__ eidx1, int* __restrict__ eidx2,
                            int E1, int E2) {
    int g = blockIdx.x * 256 + threadIdx.x;
    if (g < E1) {
        int d = dst1[g];
        eidx1[rs1[d] + posE[g]] = src1[g];
    } else if (g < E1 + E2) {
        int gg = g - E1;
        int d = dst2[gg];
        eidx2[rs2[d] + posE[g]] = src2[gg];
    }
}

// ---------------- canonicalize CSR: sort each segment ascending ----------------
// posE assignment order is nondeterministic per replay; sorted segments are a
// pure function of the inputs -> bit-identical aggregation on every replay.
__global__ __launch_bounds__(256)
void sort_k(const int* __restrict__ rs1, int* __restrict__ eidx1,
            const int* __restrict__ rs2, int* __restrict__ eidx2) {
    int node = blockIdx.x * 4 + (threadIdx.x >> 6);
    const int* rs; int* e;
    if (node < N1) { rs = rs1; e = eidx1; }
    else if (node < N1 + N2) { rs = rs2; e = eidx2; node -= N1; }
    else return;
    int l = threadIdx.x & 63;
    int s = rs[node], t = rs[node + 1];
    int deg = t - s;
    if (deg <= 1) return;
    if (deg <= 64) {
        int v = (l < deg) ? e[s + l] : 0x7FFFFFFF;
#pragma unroll
        for (int k = 2; k <= 64; k <<= 1) {
#pragma unroll
            for (int j = k >> 1; j > 0; j >>= 1) {
                int pv = __shfl_xor(v, j);
                bool lower = (l & j) == 0;
                bool asc = (l & k) == 0;
                int mn = min(v, pv), mx = max(v, pv);
                v = (lower == asc) ? mn : mx;
            }
        }
        if (l < deg) e[s + l] = v;
    } else if (l == 0) {
        // ultra-rare tail: serial insertion sort
        for (int i = s + 1; i < t; ++i) {
            int v = e[i]; int j = i - 1;
            while (j >= s && e[j] > v) { e[j + 1] = e[j]; --j; }
            e[j + 1] = v;
        }
    }
}

// ---------------- aggregation: one wave per node, 8-edge unroll ----------------
__global__ __launch_bounds__(256)
void agg_bf16_k(const unsigned short* __restrict__ x, const int* __restrict__ rs,
                const int* __restrict__ eidx, unsigned short* __restrict__ out, int n) {
    int node = blockIdx.x * 4 + (threadIdx.x >> 6);
    if (node >= n) return;
    int l = threadIdx.x & 63;
    int s = rs[node], e = rs[node + 1];
    float acc[8] = {};
    int i = s;
    for (; i + 8 <= e; i += 8) {
        uint4 v[8];
#pragma unroll
        for (int u = 0; u < 8; ++u)
            v[u] = *(const uint4*)(x + (size_t)eidx[i + u] * HH + l * 8);
#pragma unroll
        for (int u = 0; u < 8; ++u) {
            const unsigned short* pv = (const unsigned short*)&v[u];
#pragma unroll
            for (int j = 0; j < 8; ++j) acc[j] += bf2f(pv[j]);
        }
    }
    for (; i < e; ++i) {
        uint4 a = *(const uint4*)(x + (size_t)eidx[i] * HH + l * 8);
        const unsigned short* pa = (const unsigned short*)&a;
#pragma unroll
        for (int j = 0; j < 8; ++j) acc[j] += bf2f(pa[j]);
    }
    unsigned short o[8];
#pragma unroll
    for (int j = 0; j < 8; ++j) o[j] = f2bf(acc[j]);
    *(uint4*)(out + (size_t)node * HH + l * 8) = *(const uint4*)o;
}

// ---------------- bf16 MFMA GEMM (layer 1, dual fused in k-loop) ----------------
// h = relu(agg1@Wrel1^T' + x@Wroot1^T' + b); Bt inputs are [N][K] bf16.
__global__ __launch_bounds__(256)
void gemm_mfma_k(const short* __restrict__ A1, const short* __restrict__ B1t,
                 const short* __restrict__ A2, const short* __restrict__ B2t,
                 const float* __restrict__ bias, unsigned short* __restrict__ Cout,
                 int M) {
    __shared__ __align__(16) short Ls[4 * 128 * 32];   // A1 | A2 | B1 | B2 (32 KB)
    short* As1 = Ls;
    short* As2 = Ls + 4096;
    short* Bs1 = Ls + 8192;
    short* Bs2 = Ls + 12288;
    const int bn = blockIdx.x * 128;
    const int bm = blockIdx.y * 128;
    const int tid = threadIdx.x;
    const int lane = tid & 63;
    const int wave = tid >> 6;
    const int l15 = lane & 15;
    const int quad = lane >> 4;
    const int wm = (wave >> 1) * 64;
    const int wn = (wave & 1) * 64;
    const int r0 = tid >> 2;          // 0..63
    const int sg = (tid & 3) * 8;     // bf16 offset in 32-k row

    f32x4 acc[4][4] = {};

    for (int k0 = 0; k0 < 512; k0 += 32) {
        gld16(A1 + (size_t)(bm + r0) * 512 + k0 + sg,        As1 + tid * 8);
        gld16(A1 + (size_t)(bm + r0 + 64) * 512 + k0 + sg,   As1 + (tid + 256) * 8);
        gld16(A2 + (size_t)(bm + r0) * 512 + k0 + sg,        As2 + tid * 8);
        gld16(A2 + (size_t)(bm + r0 + 64) * 512 + k0 + sg,   As2 + (tid + 256) * 8);
        gld16(B1t + (size_t)(bn + r0) * 512 + k0 + sg,       Bs1 + tid * 8);
        gld16(B1t + (size_t)(bn + r0 + 64) * 512 + k0 + sg,  Bs1 + (tid + 256) * 8);
        gld16(B2t + (size_t)(bn + r0) * 512 + k0 + sg,       Bs2 + tid * 8);
        gld16(B2t + (size_t)(bn + r0 + 64) * 512 + k0 + sg,  Bs2 + (tid + 256) * 8);
        __syncthreads();
        {
            frag a[4], b[4];
#pragma unroll
            for (int mi = 0; mi < 4; ++mi)
                a[mi] = *(const frag*)(As1 + (wm + mi * 16 + l15) * 32 + quad * 8);
#pragma unroll
            for (int ni = 0; ni < 4; ++ni)
                b[ni] = *(const frag*)(Bs1 + (wn + ni * 16 + l15) * 32 + quad * 8);
#pragma unroll
            for (int mi = 0; mi < 4; ++mi)
#pragma unroll
                for (int ni = 0; ni < 4; ++ni)
                    acc[mi][ni] = __builtin_amdgcn_mfma_f32_16x16x32_bf16(
                        a[mi], b[ni], acc[mi][ni], 0, 0, 0);
#pragma unroll
            for (int mi = 0; mi < 4; ++mi)
                a[mi] = *(const frag*)(As2 + (wm + mi * 16 + l15) * 32 + quad * 8);
#pragma unroll
            for (int ni = 0; ni < 4; ++ni)
                b[ni] = *(const frag*)(Bs2 + (wn + ni * 16 + l15) * 32 + quad * 8);
#pragma unroll
            for (int mi = 0; mi < 4; ++mi)
#pragma unroll
                for (int ni = 0; ni < 4; ++ni)
                    acc[mi][ni] = __builtin_amdgcn_mfma_f32_16x16x32_bf16(
                        a[mi], b[ni], acc[mi][ni], 0, 0, 0);
        }
        __syncthreads();
    }

#pragma unroll
    for (int ni = 0; ni < 4; ++ni) {
        const int gn = bn + wn + ni * 16 + l15;
        const float bv = bias[gn];
#pragma unroll
        for (int mi = 0; mi < 4; ++mi) {
            const int gm0 = bm + wm + mi * 16 + quad * 4;
#pragma unroll
            for (int r = 0; r < 4; ++r) {
                const int gm = gm0 + r;
                if (gm < M) {
                    float v = fmaxf(acc[mi][ni][r] + bv, 0.f);
                    Cout[(size_t)gm * 512 + gn] = f2bf(v);
                }
            }
        }
    }
}

// ---------------- fused tail: gather + [512,10] matvec -> out ----------------
__global__ __launch_bounds__(256)
void tail_k(const unsigned short* __restrict__ h, const int* __restrict__ rs,
            const int* __restrict__ eidx,
            const float* __restrict__ W2aT, const float* __restrict__ W2bT,
            const float* __restrict__ bout, float* __restrict__ out) {
    int node = blockIdx.x * 4 + (threadIdx.x >> 6);
    if (node >= N2) return;
    int l = threadIdx.x & 63;
    int s = rs[node], e = rs[node + 1];
    float acc[8] = {};
    int i = s;
    for (; i + 4 <= e; i += 4) {
        uint4 v[4];
#pragma unroll
        for (int u = 0; u < 4; ++u)
            v[u] = *(const uint4*)(h + (size_t)eidx[i + u] * HH + l * 8);
#pragma unroll
        for (int u = 0; u < 4; ++u) {
            const unsigned short* pv = (const unsigned short*)&v[u];
#pragma unroll
            for (int j = 0; j < 8; ++j) acc[j] += bf2f(pv[j]);
        }
    }
    for (; i < e; ++i) {
        uint4 a = *(const uint4*)(h + (size_t)eidx[i] * HH + l * 8);
        const unsigned short* pa = (const unsigned short*)&a;
#pragma unroll
        for (int j = 0; j < 8; ++j) acc[j] += bf2f(pa[j]);
    }
    float r[8];
    {
        uint4 a = *(const uint4*)(h + (size_t)node * HH + l * 8);
        const unsigned short* pa = (const unsigned short*)&a;
#pragma unroll
        for (int j = 0; j < 8; ++j) r[j] = bf2f(pa[j]);
    }
    float p[C];
#pragma unroll
    for (int c = 0; c < C; ++c) {
        const float* wa = W2aT + c * HH + l * 8;
        const float* wb = W2bT + c * HH + l * 8;
        float4 wa0 = *(const float4*)wa, wa1 = *(const float4*)(wa + 4);
        float4 wb0 = *(const float4*)wb, wb1 = *(const float4*)(wb + 4);
        float v = acc[0] * wa0.x + acc[1] * wa0.y + acc[2] * wa0.z + acc[3] * wa0.w
                + acc[4] * wa1.x + acc[5] * wa1.y + acc[6] * wa1.z + acc[7] * wa1.w
                + r[0] * wb0.x + r[1] * wb0.y + r[2] * wb0.z + r[3] * wb0.w
                + r[4] * wb1.x + r[5] * wb1.y + r[6] * wb1.z + r[7] * wb1.w;
#pragma unroll
        for (int off = 32; off; off >>= 1) v += __shfl_xor(v, off);
        p[c] = v;
    }
    if (l == 0) {
#pragma unroll
        for (int c = 0; c < C; ++c) out[(size_t)node * C + c] = p[c] + bout[c];
    }
}

extern "C" void kernel_launch(void* const* d_in, const int* in_sizes, int n_in,
                              void* d_out, int out_size, void* d_ws, size_t ws_size,
                              hipStream_t stream) {
    const float* x      = (const float*)d_in[0];
    const int*   src1   = (const int*)d_in[1];
    const int*   dst1   = (const int*)d_in[2];
    const int*   src2   = (const int*)d_in[3];
    const int*   dst2   = (const int*)d_in[4];
    const float* Wrel1  = (const float*)d_in[5];
    const float* brel1  = (const float*)d_in[6];
    const float* Wroot1 = (const float*)d_in[7];
    const float* Wrel2  = (const float*)d_in[8];
    const float* brel2  = (const float*)d_in[9];
    const float* Wroot2 = (const float*)d_in[10];
    const float* Wlin   = (const float*)d_in[11];
    const float* blin   = (const float*)d_in[12];
    const float* Whead  = (const float*)d_in[13];
    const float* bhead  = (const float*)d_in[14];
    float* out = (float*)d_out;

    const int E1 = in_sizes[1];
    const int E2 = in_sizes[3];

    // ---- workspace layout (~150 MB; ws is ~800 MB per fill evidence) ----
    char* w = (char*)d_ws;
    auto alloc = [&](size_t bytes) { char* p = w; w += (bytes + 255) & ~(size_t)255; return p; };
    unsigned short* xb    = (unsigned short*)alloc((size_t)N0 * HH * 2);
    unsigned short* agg1b = (unsigned short*)alloc((size_t)M1PAD * HH * 2);
    unsigned short* hb    = (unsigned short*)alloc((size_t)M1PAD * HH * 2);
    unsigned short* Wt    = (unsigned short*)alloc((size_t)2 * HH * HH * 2);
    float* P1    = (float*)alloc((size_t)HH * C * 4);
    float* W2aT  = (float*)alloc((size_t)HH * C * 4);
    float* W2bT  = (float*)alloc((size_t)HH * C * 4);
    float* boutp = (float*)alloc(256);
    int* ip = (int*)alloc((size_t)(N1 + N2 + (N1 + 1) + (N2 + 1) + 2 * (E1 + E2)) * 4);
    int* cnt1  = ip;
    int* cnt2  = ip + N1;
    int* rs1   = ip + N1 + N2;
    int* rs2   = rs1 + N1 + 1;
    int* eidx1 = rs2 + N2 + 1;
    int* eidx2 = eidx1 + E1;
    int* posE  = eidx2 + E2;

    const short* Wrel1t  = (const short*)(Wt);
    const short* Wroot1t = (const short*)(Wt + (size_t)HH * HH);

    hipMemsetAsync(ip, 0, (size_t)(N1 + N2) * sizeof(int), stream);

    // ---- prep1: P1 + castw + count(pos) + castx ----
    const int nbCount = (E1 + E2 + 255) / 256;
    const int nbCast  = N0 * HH / 16 / 256;   // 12500 (16 elem/thread)
    prep1_k<<<20 + 512 + nbCount + nbCast, 256, 0, stream>>>(
        dst1, dst2, cnt1, cnt2, posE, E1, E2, x, xb, Wrel1, Wroot1, Wt,
        Wlin, Whead, P1, nbCount);

    // ---- prep2: exscans + W2aT/W2bT + bout ----
    prep2_k<<<13, 1024, 0, stream>>>(cnt1, rs1, cnt2, rs2, Wrel2, Wroot2, P1,
                                     brel2, blin, Whead, bhead, W2aT, W2bT, boutp);

    // ---- CSR fill (atomic-free) ----
    fill_both_k<<<nbCount, 256, 0, stream>>>(src1, dst1, src2, dst2, rs1, rs2,
                                             posE, eidx1, eidx2, E1, E2);

    // ---- canonicalize adjacency order (determinism across replays) ----
    sort_k<<<(N1 + N2 + 3) / 4, 256, 0, stream>>>(rs1, eidx1, rs2, eidx2);

    // ---- layer 1 ----
    agg_bf16_k<<<(N1 + 3) / 4, 256, 0, stream>>>(xb, rs1, eidx1, agg1b, N1);
    {
        dim3 grid(HH / 128, M1PAD / 128);
        gemm_mfma_k<<<grid, 256, 0, stream>>>(
            (const short*)agg1b, Wrel1t, (const short*)xb, Wroot1t, brel1, hb, N1);
    }

    // ---- fused layer 2 + head ----
    tail_k<<<(N2 + 3) / 4, 256, 0, stream>>>(hb, rs2, eidx2, W2aT, W2bT, boutp, out);
}

// Round 3
// 510.636 us; speedup vs baseline: 1.2661x; 1.0483x over previous
//
#include <hip/hip_runtime.h>
#include <hip/hip_bf16.h>
#include <cstdint>

// GCN: 2-layer GraphConv + dense head on MI355X. Round 7:
//  - prep1: edge-count atomics FUSED into cast blocks (48 edges/block, issued
//    before the cast's streaming loads) -> atomic latency hides under the
//    HBM-streaming phase instead of running as a separate all-atomic phase
//    with the BW pipe idle. (R6 evidence: prep1 127us @ 22% HBM, 3% VALU,
//    0 MFMA -> phases were time-sharing, not overlapping.)
//  - atomic-free CSR fill via posE; sort_k canonicalizes for replay determinism
//  - 8 total dispatches (memset + 7 kernels)

static constexpr int N0 = 100000;
static constexpr int N1 = 20000;
static constexpr int N2 = 4000;
static constexpr int HH = 512;
static constexpr int C  = 10;
static constexpr int M1PAD = 20096;  // 157 * 128

using frag  = __attribute__((ext_vector_type(8))) short;
using f32x4 = __attribute__((ext_vector_type(4))) float;

__device__ inline float bf2f(unsigned short u) {
    unsigned t = ((unsigned)u) << 16; float f; __builtin_memcpy(&f, &t, 4); return f;
}
__device__ inline unsigned short f2bf(float f) {
    unsigned u; __builtin_memcpy(&u, &f, 4);
    u += 0x7FFFu + ((u >> 16) & 1u);  // RNE
    return (unsigned short)(u >> 16);
}
__device__ inline void gld16(const void* g, void* l) {
    __builtin_amdgcn_global_load_lds((const __attribute__((address_space(1))) void*)g,
                                     (__attribute__((address_space(3))) void*)l,
                                     16, 0, 0);
}

// ---------------- prep1: P1 + weight cast + fused [x cast + edge count] -----
__global__ __launch_bounds__(256)
void prep1_k(const int* __restrict__ dst1, const int* __restrict__ dst2,
             int* __restrict__ cnt1, int* __restrict__ cnt2, int* __restrict__ posE,
             int E1, int E2,
             const float* __restrict__ x, unsigned short* __restrict__ xb,
             const float* __restrict__ Wrel1, const float* __restrict__ Wroot1,
             unsigned short* __restrict__ Wt,
             const float* __restrict__ Wlin, const float* __restrict__ Whead,
             float* __restrict__ P1,
             int epb) {
    __shared__ float sh[5120];   // 20 KB: Whead tile / transpose tile
    int b = blockIdx.x;
    const int tid = threadIdx.x;
    if (b < 20) {                            // ---- P1 = Wlin @ Whead ----
        for (int i = tid; i < HH * C; i += 256) sh[i] = Whead[i];
        __syncthreads();
        int g = b * 256 + tid;               // 0..5119
        int k = g / C, c = g % C;
        const float4* rp = (const float4*)(Wlin + (size_t)k * HH);
        float a0 = 0.f, a1 = 0.f, a2 = 0.f, a3 = 0.f;
#pragma unroll 4
        for (int j = 0; j < HH / 4; ++j) {
            float4 v = rp[j];
            int j4 = j * 4;
            a0 += v.x * sh[(j4    ) * C + c];
            a1 += v.y * sh[(j4 + 1) * C + c];
            a2 += v.z * sh[(j4 + 2) * C + c];
            a3 += v.w * sh[(j4 + 3) * C + c];
        }
        P1[g] = (a0 + a1) + (a2 + a3);
        return;
    }
    b -= 20;
    if (b < 512) {                           // ---- weight transpose+cast ----
        int z = b >> 8, rem = b & 255;
        int bx = (rem & 15) * 32, by = (rem >> 4) * 32;
        const float* W = z ? Wroot1 : Wrel1;
        unsigned short* O = Wt + (size_t)z * HH * HH;
        int tx = tid & 31, ty = tid >> 5;
#pragma unroll
        for (int i = 0; i < 4; ++i)
            sh[(ty + i * 8) * 33 + tx] = W[(size_t)(by + ty + i * 8) * HH + bx + tx];
        __syncthreads();
#pragma unroll
        for (int i = 0; i < 4; ++i)
            O[(size_t)(bx + ty + i * 8) * HH + by + tx] = f2bf(sh[tx * 33 + ty + i * 8]);
        return;
    }
    b -= 512;
    {                             // ---- fused: edge count (48/blk) + x cast ----
        // issue the scattered atomic FIRST so its latency hides under the
        // streaming cast below; result consumed only at the posE store.
        int eg = b * epb + tid;
        bool hasE = (tid < epb) && (eg < E1 + E2);
        int pos = 0;
        if (hasE) {
            if (eg < E1) pos = atomicAdd(&cnt1[dst1[eg]], 1);
            else         pos = atomicAdd(&cnt2[dst2[eg - E1]], 1);
        }
        int g = b * 256 + tid;               // 16 floats per thread
        const float4* p = (const float4*)x + (size_t)g * 4;
        float4 v0 = p[0], v1 = p[1], v2 = p[2], v3 = p[3];
        unsigned short t[16] = {f2bf(v0.x), f2bf(v0.y), f2bf(v0.z), f2bf(v0.w),
                                f2bf(v1.x), f2bf(v1.y), f2bf(v1.z), f2bf(v1.w),
                                f2bf(v2.x), f2bf(v2.y), f2bf(v2.z), f2bf(v2.w),
                                f2bf(v3.x), f2bf(v3.y), f2bf(v3.z), f2bf(v3.w)};
        uint4* o = (uint4*)(xb + (size_t)g * 16);
        o[0] = ((const uint4*)t)[0];
        o[1] = ((const uint4*)t)[1];
        if (hasE) posE[eg] = pos;
    }
}

// ---------------- prep2: two exscans + W2aT/W2bT + bout ----------------
__global__ __launch_bounds__(1024)
void prep2_k(const int* __restrict__ cnt1, int* __restrict__ rs1,
             const int* __restrict__ cnt2, int* __restrict__ rs2,
             const float* __restrict__ Wrel2, const float* __restrict__ Wroot2,
             const float* __restrict__ P1,
             const float* __restrict__ brel2, const float* __restrict__ blin,
             const float* __restrict__ Whead, const float* __restrict__ bhead,
             float* __restrict__ W2aT, float* __restrict__ W2bT,
             float* __restrict__ bout) {
    __shared__ float fsh[5120];              // 20 KB: scan ints / P1 tile / reduce
    int* part = (int*)fsh;
    int blk = blockIdx.x;
    int t = threadIdx.x;
    if (blk < 2) {                           // ---- exclusive scans ----
        const int* cnt = blk ? cnt2 : cnt1;
        int* rs = blk ? rs2 : rs1;
        int n = blk ? N2 : N1;
        int chunk = (n + 1023) >> 10;
        int bb = t * chunk;
        int e = min(bb + chunk, n);
        int s = 0;
        for (int i = bb; i < e; ++i) s += cnt[i];
        part[t] = s;
        __syncthreads();
        for (int off = 1; off < 1024; off <<= 1) {
            int add = (t >= off) ? part[t - off] : 0;
            __syncthreads();
            part[t] += add;
            __syncthreads();
        }
        int base = (t == 0) ? 0 : part[t - 1];
        for (int i = bb; i < e; ++i) { rs[i] = base; base += cnt[i]; }
        if (t == 1023) rs[n] = part[1023];
        return;
    }
    if (blk < 12) {                          // ---- W2aT / W2bT (P1 staged in LDS) ----
        for (int i = t; i < HH * C; i += 1024) fsh[i] = P1[i];
        __syncthreads();
        int z = (blk - 2) >= 5;
        int g = (blk - 2 - z * 5) * 1024 + t;
        if (g < HH * C) {
            const float* W = z ? Wroot2 : Wrel2;
            float* O = z ? W2bT : W2aT;
            int k = g / C, c = g % C;
            const float4* rp = (const float4*)(W + (size_t)k * HH);
            float a0 = 0.f, a1 = 0.f, a2 = 0.f, a3 = 0.f;
#pragma unroll 4
            for (int j = 0; j < HH / 4; ++j) {
                float4 v = rp[j];
                int j4 = j * 4;
                a0 += v.x * fsh[(j4    ) * C + c];
                a1 += v.y * fsh[(j4 + 1) * C + c];
                a2 += v.z * fsh[(j4 + 2) * C + c];
                a3 += v.w * fsh[(j4 + 3) * C + c];
            }
            O[c * HH + k] = (a0 + a1) + (a2 + a3);   // transposed [10][512]
        }
        return;
    }
    {                                        // ---- bout: parallel over j + reduce ----
        float pr[C];
#pragma unroll
        for (int c = 0; c < C; ++c) pr[c] = 0.f;
        if (t < HH) {
            float br = brel2[t], bl = blin[t];
            const float* p1r = P1 + (size_t)t * C;
            const float* whr = Whead + (size_t)t * C;
#pragma unroll
            for (int c = 0; c < C; ++c) pr[c] = br * p1r[c] + bl * whr[c];
        }
#pragma unroll
        for (int c = 0; c < C; ++c)
#pragma unroll
            for (int off = 32; off; off >>= 1) pr[c] += __shfl_xor(pr[c], off);
        int wv = t >> 6, ln = t & 63;
        if (ln == 0)
#pragma unroll
            for (int c = 0; c < C; ++c) fsh[wv * C + c] = pr[c];
        __syncthreads();
        if (t < C) {
            float acc = bhead[t];
#pragma unroll
            for (int w = 0; w < 16; ++w) acc += fsh[w * C + t];
            bout[t] = acc;
        }
    }
}

// ---------------- CSR fill (atomic-free: positions from count pass) ----------------
__global__ void fill_both_k(const int* __restrict__ src1, const int* __restrict__ dst1,
                            const int* __restrict__ src2, const int* __restrict__ dst2,
                            const int* __restrict__ rs1, const int* __restrict__ rs2,
                            const int* __restrict__ posE,
                            int* __restrict__ eidx1, int* __restrict__ eidx2,
                            int E1, int E2) {
    int g = blockIdx.x * 256 + threadIdx.x;
    if (g < E1) {
        int d = dst1[g];
        eidx1[rs1[d] + posE[g]] = src1[g];
    } else if (g < E1 + E2) {
        int gg = g - E1;
        int d = dst2[gg];
        eidx2[rs2[d] + posE[g]] = src2[gg];
    }
}

// ---------------- canonicalize CSR: sort each segment ascending ----------------
// posE assignment order is nondeterministic per replay; sorted segments are a
// pure function of the inputs -> bit-identical aggregation on every replay.
__global__ __launch_bounds__(256)
void sort_k(const int* __restrict__ rs1, int* __restrict__ eidx1,
            const int* __restrict__ rs2, int* __restrict__ eidx2) {
    int node = blockIdx.x * 4 + (threadIdx.x >> 6);
    const int* rs; int* e;
    if (node < N1) { rs = rs1; e = eidx1; }
    else if (node < N1 + N2) { rs = rs2; e = eidx2; node -= N1; }
    else return;
    int l = threadIdx.x & 63;
    int s = rs[node], t = rs[node + 1];
    int deg = t - s;
    if (deg <= 1) return;
    if (deg <= 64) {
        int v = (l < deg) ? e[s + l] : 0x7FFFFFFF;
#pragma unroll
        for (int k = 2; k <= 64; k <<= 1) {
#pragma unroll
            for (int j = k >> 1; j > 0; j >>= 1) {
                int pv = __shfl_xor(v, j);
                bool lower = (l & j) == 0;
                bool asc = (l & k) == 0;
                int mn = min(v, pv), mx = max(v, pv);
                v = (lower == asc) ? mn : mx;
            }
        }
        if (l < deg) e[s + l] = v;
    } else if (l == 0) {
        // ultra-rare tail: serial insertion sort
        for (int i = s + 1; i < t; ++i) {
            int v = e[i]; int j = i - 1;
            while (j >= s && e[j] > v) { e[j + 1] = e[j]; --j; }
            e[j + 1] = v;
        }
    }
}

// ---------------- aggregation: one wave per node, 8-edge unroll ----------------
__global__ __launch_bounds__(256)
void agg_bf16_k(const unsigned short* __restrict__ x, const int* __restrict__ rs,
                const int* __restrict__ eidx, unsigned short* __restrict__ out, int n) {
    int node = blockIdx.x * 4 + (threadIdx.x >> 6);
    if (node >= n) return;
    int l = threadIdx.x & 63;
    int s = rs[node], e = rs[node + 1];
    float acc[8] = {};
    int i = s;
    for (; i + 8 <= e; i += 8) {
        uint4 v[8];
#pragma unroll
        for (int u = 0; u < 8; ++u)
            v[u] = *(const uint4*)(x + (size_t)eidx[i + u] * HH + l * 8);
#pragma unroll
        for (int u = 0; u < 8; ++u) {
            const unsigned short* pv = (const unsigned short*)&v[u];
#pragma unroll
            for (int j = 0; j < 8; ++j) acc[j] += bf2f(pv[j]);
        }
    }
    for (; i < e; ++i) {
        uint4 a = *(const uint4*)(x + (size_t)eidx[i] * HH + l * 8);
        const unsigned short* pa = (const unsigned short*)&a;
#pragma unroll
        for (int j = 0; j < 8; ++j) acc[j] += bf2f(pa[j]);
    }
    unsigned short o[8];
#pragma unroll
    for (int j = 0; j < 8; ++j) o[j] = f2bf(acc[j]);
    *(uint4*)(out + (size_t)node * HH + l * 8) = *(const uint4*)o;
}

// ---------------- bf16 MFMA GEMM (layer 1, dual fused in k-loop) ----------------
// h = relu(agg1@Wrel1^T' + x@Wroot1^T' + b); Bt inputs are [N][K] bf16.
__global__ __launch_bounds__(256)
void gemm_mfma_k(const short* __restrict__ A1, const short* __restrict__ B1t,
                 const short* __restrict__ A2, const short* __restrict__ B2t,
                 const float* __restrict__ bias, unsigned short* __restrict__ Cout,
                 int M) {
    __shared__ __align__(16) short Ls[4 * 128 * 32];   // A1 | A2 | B1 | B2 (32 KB)
    short* As1 = Ls;
    short* As2 = Ls + 4096;
    short* Bs1 = Ls + 8192;
    short* Bs2 = Ls + 12288;
    const int bn = blockIdx.x * 128;
    const int bm = blockIdx.y * 128;
    const int tid = threadIdx.x;
    const int lane = tid & 63;
    const int wave = tid >> 6;
    const int l15 = lane & 15;
    const int quad = lane >> 4;
    const int wm = (wave >> 1) * 64;
    const int wn = (wave & 1) * 64;
    const int r0 = tid >> 2;          // 0..63
    const int sg = (tid & 3) * 8;     // bf16 offset in 32-k row

    f32x4 acc[4][4] = {};

    for (int k0 = 0; k0 < 512; k0 += 32) {
        gld16(A1 + (size_t)(bm + r0) * 512 + k0 + sg,        As1 + tid * 8);
        gld16(A1 + (size_t)(bm + r0 + 64) * 512 + k0 + sg,   As1 + (tid + 256) * 8);
        gld16(A2 + (size_t)(bm + r0) * 512 + k0 + sg,        As2 + tid * 8);
        gld16(A2 + (size_t)(bm + r0 + 64) * 512 + k0 + sg,   As2 + (tid + 256) * 8);
        gld16(B1t + (size_t)(bn + r0) * 512 + k0 + sg,       Bs1 + tid * 8);
        gld16(B1t + (size_t)(bn + r0 + 64) * 512 + k0 + sg,  Bs1 + (tid + 256) * 8);
        gld16(B2t + (size_t)(bn + r0) * 512 + k0 + sg,       Bs2 + tid * 8);
        gld16(B2t + (size_t)(bn + r0 + 64) * 512 + k0 + sg,  Bs2 + (tid + 256) * 8);
        __syncthreads();
        {
            frag a[4], b[4];
#pragma unroll
            for (int mi = 0; mi < 4; ++mi)
                a[mi] = *(const frag*)(As1 + (wm + mi * 16 + l15) * 32 + quad * 8);
#pragma unroll
            for (int ni = 0; ni < 4; ++ni)
                b[ni] = *(const frag*)(Bs1 + (wn + ni * 16 + l15) * 32 + quad * 8);
#pragma unroll
            for (int mi = 0; mi < 4; ++mi)
#pragma unroll
                for (int ni = 0; ni < 4; ++ni)
                    acc[mi][ni] = __builtin_amdgcn_mfma_f32_16x16x32_bf16(
                        a[mi], b[ni], acc[mi][ni], 0, 0, 0);
#pragma unroll
            for (int mi = 0; mi < 4; ++mi)
                a[mi] = *(const frag*)(As2 + (wm + mi * 16 + l15) * 32 + quad * 8);
#pragma unroll
            for (int ni = 0; ni < 4; ++ni)
                b[ni] = *(const frag*)(Bs2 + (wn + ni * 16 + l15) * 32 + quad * 8);
#pragma unroll
            for (int mi = 0; mi < 4; ++mi)
#pragma unroll
                for (int ni = 0; ni < 4; ++ni)
                    acc[mi][ni] = __builtin_amdgcn_mfma_f32_16x16x32_bf16(
                        a[mi], b[ni], acc[mi][ni], 0, 0, 0);
        }
        __syncthreads();
    }

#pragma unroll
    for (int ni = 0; ni < 4; ++ni) {
        const int gn = bn + wn + ni * 16 + l15;
        const float bv = bias[gn];
#pragma unroll
        for (int mi = 0; mi < 4; ++mi) {
            const int gm0 = bm + wm + mi * 16 + quad * 4;
#pragma unroll
            for (int r = 0; r < 4; ++r) {
                const int gm = gm0 + r;
                if (gm < M) {
                    float v = fmaxf(acc[mi][ni][r] + bv, 0.f);
                    Cout[(size_t)gm * 512 + gn] = f2bf(v);
                }
            }
        }
    }
}

// ---------------- fused tail: gather + [512,10] matvec -> out ----------------
__global__ __launch_bounds__(256)
void tail_k(const unsigned short* __restrict__ h, const int* __restrict__ rs,
            const int* __restrict__ eidx,
            const float* __restrict__ W2aT, const float* __restrict__ W2bT,
            const float* __restrict__ bout, float* __restrict__ out) {
    int node = blockIdx.x * 4 + (threadIdx.x >> 6);
    if (node >= N2) return;
    int l = threadIdx.x & 63;
    int s = rs[node], e = rs[node + 1];
    float acc[8] = {};
    int i = s;
    for (; i + 4 <= e; i += 4) {
        uint4 v[4];
#pragma unroll
        for (int u = 0; u < 4; ++u)
            v[u] = *(const uint4*)(h + (size_t)eidx[i + u] * HH + l * 8);
#pragma unroll
        for (int u = 0; u < 4; ++u) {
            const unsigned short* pv = (const unsigned short*)&v[u];
#pragma unroll
            for (int j = 0; j < 8; ++j) acc[j] += bf2f(pv[j]);
        }
    }
    for (; i < e; ++i) {
        uint4 a = *(const uint4*)(h + (size_t)eidx[i] * HH + l * 8);
        const unsigned short* pa = (const unsigned short*)&a;
#pragma unroll
        for (int j = 0; j < 8; ++j) acc[j] += bf2f(pa[j]);
    }
    float r[8];
    {
        uint4 a = *(const uint4*)(h + (size_t)node * HH + l * 8);
        const unsigned short* pa = (const unsigned short*)&a;
#pragma unroll
        for (int j = 0; j < 8; ++j) r[j] = bf2f(pa[j]);
    }
    float p[C];
#pragma unroll
    for (int c = 0; c < C; ++c) {
        const float* wa = W2aT + c * HH + l * 8;
        const float* wb = W2bT + c * HH + l * 8;
        float4 wa0 = *(const float4*)wa, wa1 = *(const float4*)(wa + 4);
        float4 wb0 = *(const float4*)wb, wb1 = *(const float4*)(wb + 4);
        float v = acc[0] * wa0.x + acc[1] * wa0.y + acc[2] * wa0.z + acc[3] * wa0.w
                + acc[4] * wa1.x + acc[5] * wa1.y + acc[6] * wa1.z + acc[7] * wa1.w
                + r[0] * wb0.x + r[1] * wb0.y + r[2] * wb0.z + r[3] * wb0.w
                + r[4] * wb1.x + r[5] * wb1.y + r[6] * wb1.z + r[7] * wb1.w;
#pragma unroll
        for (int off = 32; off; off >>= 1) v += __shfl_xor(v, off);
        p[c] = v;
    }
    if (l == 0) {
#pragma unroll
        for (int c = 0; c < C; ++c) out[(size_t)node * C + c] = p[c] + bout[c];
    }
}

extern "C" void kernel_launch(void* const* d_in, const int* in_sizes, int n_in,
                              void* d_out, int out_size, void* d_ws, size_t ws_size,
                              hipStream_t stream) {
    const float* x      = (const float*)d_in[0];
    const int*   src1   = (const int*)d_in[1];
    const int*   dst1   = (const int*)d_in[2];
    const int*   src2   = (const int*)d_in[3];
    const int*   dst2   = (const int*)d_in[4];
    const float* Wrel1  = (const float*)d_in[5];
    const float* brel1  = (const float*)d_in[6];
    const float* Wroot1 = (const float*)d_in[7];
    const float* Wrel2  = (const float*)d_in[8];
    const float* brel2  = (const float*)d_in[9];
    const float* Wroot2 = (const float*)d_in[10];
    const float* Wlin   = (const float*)d_in[11];
    const float* blin   = (const float*)d_in[12];
    const float* Whead  = (const float*)d_in[13];
    const float* bhead  = (const float*)d_in[14];
    float* out = (float*)d_out;

    const int E1 = in_sizes[1];
    const int E2 = in_sizes[3];

    // ---- workspace layout (~150 MB; ws is ~800 MB per fill evidence) ----
    char* w = (char*)d_ws;
    auto alloc = [&](size_t bytes) { char* p = w; w += (bytes + 255) & ~(size_t)255; return p; };
    unsigned short* xb    = (unsigned short*)alloc((size_t)N0 * HH * 2);
    unsigned short* agg1b = (unsigned short*)alloc((size_t)M1PAD * HH * 2);
    unsigned short* hb    = (unsigned short*)alloc((size_t)M1PAD * HH * 2);
    unsigned short* Wt    = (unsigned short*)alloc((size_t)2 * HH * HH * 2);
    float* P1    = (float*)alloc((size_t)HH * C * 4);
    float* W2aT  = (float*)alloc((size_t)HH * C * 4);
    float* W2bT  = (float*)alloc((size_t)HH * C * 4);
    float* boutp = (float*)alloc(256);
    int* ip = (int*)alloc((size_t)(N1 + N2 + (N1 + 1) + (N2 + 1) + 2 * (E1 + E2)) * 4);
    int* cnt1  = ip;
    int* cnt2  = ip + N1;
    int* rs1   = ip + N1 + N2;
    int* rs2   = rs1 + N1 + 1;
    int* eidx1 = rs2 + N2 + 1;
    int* eidx2 = eidx1 + E1;
    int* posE  = eidx2 + E2;

    const short* Wrel1t  = (const short*)(Wt);
    const short* Wroot1t = (const short*)(Wt + (size_t)HH * HH);

    hipMemsetAsync(ip, 0, (size_t)(N1 + N2) * sizeof(int), stream);

    // ---- prep1: P1 + castw + fused [castx + count(pos)] ----
    const int nbCast = N0 * HH / 16 / 256;   // 12500 (16 elem/thread)
    const int epb    = (E1 + E2 + nbCast - 1) / nbCast;   // 48 edges per cast block
    prep1_k<<<20 + 512 + nbCast, 256, 0, stream>>>(
        dst1, dst2, cnt1, cnt2, posE, E1, E2, x, xb, Wrel1, Wroot1, Wt,
        Wlin, Whead, P1, epb);

    // ---- prep2: exscans + W2aT/W2bT + bout ----
    prep2_k<<<13, 1024, 0, stream>>>(cnt1, rs1, cnt2, rs2, Wrel2, Wroot2, P1,
                                     brel2, blin, Whead, bhead, W2aT, W2bT, boutp);

    // ---- CSR fill (atomic-free) ----
    const int nbFill = (E1 + E2 + 255) / 256;
    fill_both_k<<<nbFill, 256, 0, stream>>>(src1, dst1, src2, dst2, rs1, rs2,
                                            posE, eidx1, eidx2, E1, E2);

    // ---- canonicalize adjacency order (determinism across replays) ----
    sort_k<<<(N1 + N2 + 3) / 4, 256, 0, stream>>>(rs1, eidx1, rs2, eidx2);

    // ---- layer 1 ----
    agg_bf16_k<<<(N1 + 3) / 4, 256, 0, stream>>>(xb, rs1, eidx1, agg1b, N1);
    {
        dim3 grid(HH / 128, M1PAD / 128);
        gemm_mfma_k<<<grid, 256, 0, stream>>>(
            (const short*)agg1b, Wrel1t, (const short*)xb, Wroot1t, brel1, hb, N1);
    }

    // ---- fused layer 2 + head ----
    tail_k<<<(N2 + 3) / 4, 256, 0, stream>>>(hb, rs2, eidx2, W2aT, W2bT, boutp, out);
}

// Round 5
// 500.261 us; speedup vs baseline: 1.2923x; 1.0207x over previous
//
#include <hip/hip_runtime.h>
#include <hip/hip_bf16.h>
#include <cstdint>

// GCN: 2-layer GraphConv + dense head on MI355X. Round 8 (resubmit; prior run
// died to container infra failure, not kernel error):
//  - SLOT CSR: fixed 128-entry slot per node; the count atomic directly places
//    each edge (eidx[d*128+pos]) -> fill_both_k, posE, and both exscans deleted.
//  - INT AGGREGATION: fixed-point int32 segment sums (agg x2^20, tail x2^18) are
//    order-independent -> sort_k deleted; replay determinism preserved exactly.
//  - 6 dispatches: memset + prep1 + prep2 + agg + gemm + tail
//  - prep1 fuses: P1 + weight transpose/cast + [x cast + edge count&place]

static constexpr int N0 = 100000;
static constexpr int N1 = 20000;
static constexpr int N2 = 4000;
static constexpr int HH = 512;
static constexpr int C  = 10;
static constexpr int M1PAD = 20096;  // 157 * 128
static constexpr int SLOT = 128;     // per-node adjacency capacity (deg~Pois(25))

using frag  = __attribute__((ext_vector_type(8))) short;
using f32x4 = __attribute__((ext_vector_type(4))) float;

__device__ inline float bf2f(unsigned short u) {
    unsigned t = ((unsigned)u) << 16; float f; __builtin_memcpy(&f, &t, 4); return f;
}
__device__ inline unsigned short f2bf(float f) {
    unsigned u; __builtin_memcpy(&u, &f, 4);
    u += 0x7FFFu + ((u >> 16) & 1u);  // RNE
    return (unsigned short)(u >> 16);
}
__device__ inline void gld16(const void* g, void* l) {
    __builtin_amdgcn_global_load_lds((const __attribute__((address_space(1))) void*)g,
                                     (__attribute__((address_space(3))) void*)l,
                                     16, 0, 0);
}

// ---- prep1: P1 + weight cast + fused [x cast + edge count&place] ----
__global__ __launch_bounds__(256)
void prep1_k(const int* __restrict__ src1, const int* __restrict__ dst1,
             const int* __restrict__ src2, const int* __restrict__ dst2,
             int* __restrict__ cnt1, int* __restrict__ cnt2,
             int* __restrict__ eidx1, int* __restrict__ eidx2,
             int E1, int E2,
             const float* __restrict__ x, unsigned short* __restrict__ xb,
             const float* __restrict__ Wrel1, const float* __restrict__ Wroot1,
             unsigned short* __restrict__ Wt,
             const float* __restrict__ Wlin, const float* __restrict__ Whead,
             float* __restrict__ P1,
             int epb) {
    __shared__ float sh[5120];   // 20 KB: Whead tile / transpose tile
    int b = blockIdx.x;
    const int tid = threadIdx.x;
    if (b < 20) {                            // ---- P1 = Wlin @ Whead ----
        for (int i = tid; i < HH * C; i += 256) sh[i] = Whead[i];
        __syncthreads();
        int g = b * 256 + tid;               // 0..5119
        int k = g / C, c = g % C;
        const float4* rp = (const float4*)(Wlin + (size_t)k * HH);
        float a0 = 0.f, a1 = 0.f, a2 = 0.f, a3 = 0.f;
#pragma unroll 4
        for (int j = 0; j < HH / 4; ++j) {
            float4 v = rp[j];
            int j4 = j * 4;
            a0 += v.x * sh[(j4    ) * C + c];
            a1 += v.y * sh[(j4 + 1) * C + c];
            a2 += v.z * sh[(j4 + 2) * C + c];
            a3 += v.w * sh[(j4 + 3) * C + c];
        }
        P1[g] = (a0 + a1) + (a2 + a3);
        return;
    }
    b -= 20;
    if (b < 512) {                           // ---- weight transpose+cast ----
        int z = b >> 8, rem = b & 255;
        int bx = (rem & 15) * 32, by = (rem >> 4) * 32;
        const float* W = z ? Wroot1 : Wrel1;
        unsigned short* O = Wt + (size_t)z * HH * HH;
        int tx = tid & 31, ty = tid >> 5;
#pragma unroll
        for (int i = 0; i < 4; ++i)
            sh[(ty + i * 8) * 33 + tx] = W[(size_t)(by + ty + i * 8) * HH + bx + tx];
        __syncthreads();
#pragma unroll
        for (int i = 0; i < 4; ++i)
            O[(size_t)(bx + ty + i * 8) * HH + by + tx] = f2bf(sh[tx * 33 + ty + i * 8]);
        return;
    }
    b -= 512;
    {                   // ---- fused: edge count&place (epb/blk) + x cast ----
        // scattered atomic + slot store issued alongside the streaming cast so
        // their latency hides under the HBM phase (R7 evidence: -25us).
        int eg = b * epb + tid;
        bool hasE = (tid < epb) && (eg < E1 + E2);
        if (hasE) {
            if (eg < E1) {
                int d = dst1[eg];
                int pos = atomicAdd(&cnt1[d], 1);
                if (pos < SLOT) eidx1[d * SLOT + pos] = src1[eg];
            } else {
                int g2 = eg - E1;
                int d = dst2[g2];
                int pos = atomicAdd(&cnt2[d], 1);
                if (pos < SLOT) eidx2[d * SLOT + pos] = src2[g2];
            }
        }
        int g = b * 256 + tid;               // 16 floats per thread
        const float4* p = (const float4*)x + (size_t)g * 4;
        float4 v0 = p[0], v1 = p[1], v2 = p[2], v3 = p[3];
        unsigned short t[16] = {f2bf(v0.x), f2bf(v0.y), f2bf(v0.z), f2bf(v0.w),
                                f2bf(v1.x), f2bf(v1.y), f2bf(v1.z), f2bf(v1.w),
                                f2bf(v2.x), f2bf(v2.y), f2bf(v2.z), f2bf(v2.w),
                                f2bf(v3.x), f2bf(v3.y), f2bf(v3.z), f2bf(v3.w)};
        uint4* o = (uint4*)(xb + (size_t)g * 16);
        o[0] = ((const uint4*)t)[0];
        o[1] = ((const uint4*)t)[1];
    }
}

// ---------------- prep2: W2aT/W2bT + bout (scans deleted) ----------------
__global__ __launch_bounds__(1024)
void prep2_k(const float* __restrict__ Wrel2, const float* __restrict__ Wroot2,
             const float* __restrict__ P1,
             const float* __restrict__ brel2, const float* __restrict__ blin,
             const float* __restrict__ Whead, const float* __restrict__ bhead,
             float* __restrict__ W2aT, float* __restrict__ W2bT,
             float* __restrict__ bout) {
    __shared__ float fsh[5120];              // 20 KB: P1 tile / reduce
    int blk = blockIdx.x;
    int t = threadIdx.x;
    if (blk < 10) {                          // ---- W2aT / W2bT (P1 staged in LDS) ----
        for (int i = t; i < HH * C; i += 1024) fsh[i] = P1[i];
        __syncthreads();
        int z = blk >= 5;
        int g = (blk - z * 5) * 1024 + t;
        if (g < HH * C) {
            const float* W = z ? Wroot2 : Wrel2;
            float* O = z ? W2bT : W2aT;
            int k = g / C, c = g % C;
            const float4* rp = (const float4*)(W + (size_t)k * HH);
            float a0 = 0.f, a1 = 0.f, a2 = 0.f, a3 = 0.f;
#pragma unroll 4
            for (int j = 0; j < HH / 4; ++j) {
                float4 v = rp[j];
                int j4 = j * 4;
                a0 += v.x * fsh[(j4    ) * C + c];
                a1 += v.y * fsh[(j4 + 1) * C + c];
                a2 += v.z * fsh[(j4 + 2) * C + c];
                a3 += v.w * fsh[(j4 + 3) * C + c];
            }
            O[c * HH + k] = (a0 + a1) + (a2 + a3);   // transposed [10][512]
        }
        return;
    }
    {                                        // ---- bout: parallel over j + reduce ----
        float pr[C];
#pragma unroll
        for (int c = 0; c < C; ++c) pr[c] = 0.f;
        if (t < HH) {
            float br = brel2[t], bl = blin[t];
            const float* p1r = P1 + (size_t)t * C;
            const float* whr = Whead + (size_t)t * C;
#pragma unroll
            for (int c = 0; c < C; ++c) pr[c] = br * p1r[c] + bl * whr[c];
        }
#pragma unroll
        for (int c = 0; c < C; ++c)
#pragma unroll
            for (int off = 32; off; off >>= 1) pr[c] += __shfl_xor(pr[c], off);
        int wv = t >> 6, ln = t & 63;
        if (ln == 0)
#pragma unroll
            for (int c = 0; c < C; ++c) fsh[wv * C + c] = pr[c];
        __syncthreads();
        if (t < C) {
            float acc = bhead[t];
#pragma unroll
            for (int w = 0; w < 16; ++w) acc += fsh[w * C + t];
            bout[t] = acc;
        }
    }
}

// ---- aggregation: one wave per node, slot CSR, int32 fixed-point (x2^20) ----
// integer addition is associative -> result independent of slot fill order ->
// bit-identical across graph replays without any sort.
__global__ __launch_bounds__(256)
void agg_bf16_k(const unsigned short* __restrict__ x, const int* __restrict__ cnt,
                const int* __restrict__ eidx, unsigned short* __restrict__ out, int n) {
    int node = blockIdx.x * 4 + (threadIdx.x >> 6);
    if (node >= n) return;
    int l = threadIdx.x & 63;
    int deg = min(cnt[node], SLOT);
    const int* ep = eidx + (size_t)node * SLOT;
    int acc[8] = {};
    int i = 0;
    for (; i + 8 <= deg; i += 8) {
        uint4 v[8];
#pragma unroll
        for (int u = 0; u < 8; ++u)
            v[u] = *(const uint4*)(x + (size_t)ep[i + u] * HH + l * 8);
#pragma unroll
        for (int u = 0; u < 8; ++u) {
            const unsigned short* pv = (const unsigned short*)&v[u];
#pragma unroll
            for (int j = 0; j < 8; ++j) acc[j] += (int)(bf2f(pv[j]) * 1048576.0f);
        }
    }
    for (; i < deg; ++i) {
        uint4 a = *(const uint4*)(x + (size_t)ep[i] * HH + l * 8);
        const unsigned short* pa = (const unsigned short*)&a;
#pragma unroll
        for (int j = 0; j < 8; ++j) acc[j] += (int)(bf2f(pa[j]) * 1048576.0f);
    }
    unsigned short o[8];
#pragma unroll
    for (int j = 0; j < 8; ++j)
        o[j] = f2bf((float)acc[j] * (1.0f / 1048576.0f));
    *(uint4*)(out + (size_t)node * HH + l * 8) = *(const uint4*)o;
}

// ---------------- bf16 MFMA GEMM (layer 1, dual fused in k-loop) ----------------
// h = relu(agg1@Wrel1^T' + x@Wroot1^T' + b); Bt inputs are [N][K] bf16.
__global__ __launch_bounds__(256)
void gemm_mfma_k(const short* __restrict__ A1, const short* __restrict__ B1t,
                 const short* __restrict__ A2, const short* __restrict__ B2t,
                 const float* __restrict__ bias, unsigned short* __restrict__ Cout,
                 int M) {
    __shared__ __align__(16) short Ls[4 * 128 * 32];   // A1 | A2 | B1 | B2 (32 KB)
    short* As1 = Ls;
    short* As2 = Ls + 4096;
    short* Bs1 = Ls + 8192;
    short* Bs2 = Ls + 12288;
    const int bn = blockIdx.x * 128;
    const int bm = blockIdx.y * 128;
    const int tid = threadIdx.x;
    const int lane = tid & 63;
    const int wave = tid >> 6;
    const int l15 = lane & 15;
    const int quad = lane >> 4;
    const int wm = (wave >> 1) * 64;
    const int wn = (wave & 1) * 64;
    const int r0 = tid >> 2;          // 0..63
    const int sg = (tid & 3) * 8;     // bf16 offset in 32-k row

    f32x4 acc[4][4] = {};

    for (int k0 = 0; k0 < 512; k0 += 32) {
        gld16(A1 + (size_t)(bm + r0) * 512 + k0 + sg,        As1 + tid * 8);
        gld16(A1 + (size_t)(bm + r0 + 64) * 512 + k0 + sg,   As1 + (tid + 256) * 8);
        gld16(A2 + (size_t)(bm + r0) * 512 + k0 + sg,        As2 + tid * 8);
        gld16(A2 + (size_t)(bm + r0 + 64) * 512 + k0 + sg,   As2 + (tid + 256) * 8);
        gld16(B1t + (size_t)(bn + r0) * 512 + k0 + sg,       Bs1 + tid * 8);
        gld16(B1t + (size_t)(bn + r0 + 64) * 512 + k0 + sg,  Bs1 + (tid + 256) * 8);
        gld16(B2t + (size_t)(bn + r0) * 512 + k0 + sg,       Bs2 + tid * 8);
        gld16(B2t + (size_t)(bn + r0 + 64) * 512 + k0 + sg,  Bs2 + (tid + 256) * 8);
        __syncthreads();
        {
            frag a[4], b[4];
#pragma unroll
            for (int mi = 0; mi < 4; ++mi)
                a[mi] = *(const frag*)(As1 + (wm + mi * 16 + l15) * 32 + quad * 8);
#pragma unroll
            for (int ni = 0; ni < 4; ++ni)
                b[ni] = *(const frag*)(Bs1 + (wn + ni * 16 + l15) * 32 + quad * 8);
#pragma unroll
            for (int mi = 0; mi < 4; ++mi)
#pragma unroll
                for (int ni = 0; ni < 4; ++ni)
                    acc[mi][ni] = __builtin_amdgcn_mfma_f32_16x16x32_bf16(
                        a[mi], b[ni], acc[mi][ni], 0, 0, 0);
#pragma unroll
            for (int mi = 0; mi < 4; ++mi)
                a[mi] = *(const frag*)(As2 + (wm + mi * 16 + l15) * 32 + quad * 8);
#pragma unroll
            for (int ni = 0; ni < 4; ++ni)
                b[ni] = *(const frag*)(Bs2 + (wn + ni * 16 + l15) * 32 + quad * 8);
#pragma unroll
            for (int mi = 0; mi < 4; ++mi)
#pragma unroll
                for (int ni = 0; ni < 4; ++ni)
                    acc[mi][ni] = __builtin_amdgcn_mfma_f32_16x16x32_bf16(
                        a[mi], b[ni], acc[mi][ni], 0, 0, 0);
        }
        __syncthreads();
    }

#pragma unroll
    for (int ni = 0; ni < 4; ++ni) {
        const int gn = bn + wn + ni * 16 + l15;
        const float bv = bias[gn];
#pragma unroll
        for (int mi = 0; mi < 4; ++mi) {
            const int gm0 = bm + wm + mi * 16 + quad * 4;
#pragma unroll
            for (int r = 0; r < 4; ++r) {
                const int gm = gm0 + r;
                if (gm < M) {
                    float v = fmaxf(acc[mi][ni][r] + bv, 0.f);
                    Cout[(size_t)gm * 512 + gn] = f2bf(v);
                }
            }
        }
    }
}

// ---- fused tail: slot-CSR gather (int32 x2^18) + [512,10] matvec -> out ----
__global__ __launch_bounds__(256)
void tail_k(const unsigned short* __restrict__ h, const int* __restrict__ cnt,
            const int* __restrict__ eidx,
            const float* __restrict__ W2aT, const float* __restrict__ W2bT,
            const float* __restrict__ bout, float* __restrict__ out) {
    int node = blockIdx.x * 4 + (threadIdx.x >> 6);
    if (node >= N2) return;
    int l = threadIdx.x & 63;
    int deg = min(cnt[node], SLOT);
    const int* ep = eidx + (size_t)node * SLOT;
    int acci[8] = {};
    int i = 0;
    for (; i + 4 <= deg; i += 4) {
        uint4 v[4];
#pragma unroll
        for (int u = 0; u < 4; ++u)
            v[u] = *(const uint4*)(h + (size_t)ep[i + u] * HH + l * 8);
#pragma unroll
        for (int u = 0; u < 4; ++u) {
            const unsigned short* pv = (const unsigned short*)&v[u];
#pragma unroll
            for (int j = 0; j < 8; ++j) acci[j] += (int)(bf2f(pv[j]) * 262144.0f);
        }
    }
    for (; i < deg; ++i) {
        uint4 a = *(const uint4*)(h + (size_t)ep[i] * HH + l * 8);
        const unsigned short* pa = (const unsigned short*)&a;
#pragma unroll
        for (int j = 0; j < 8; ++j) acci[j] += (int)(bf2f(pa[j]) * 262144.0f);
    }
    float acc[8];
#pragma unroll
    for (int j = 0; j < 8; ++j) acc[j] = (float)acci[j] * (1.0f / 262144.0f);
    float r[8];
    {
        uint4 a = *(const uint4*)(h + (size_t)node * HH + l * 8);
        const unsigned short* pa = (const unsigned short*)&a;
#pragma unroll
        for (int j = 0; j < 8; ++j) r[j] = bf2f(pa[j]);
    }
    float p[C];
#pragma unroll
    for (int c = 0; c < C; ++c) {
        const float* wa = W2aT + c * HH + l * 8;
        const float* wb = W2bT + c * HH + l * 8;
        float4 wa0 = *(const float4*)wa, wa1 = *(const float4*)(wa + 4);
        float4 wb0 = *(const float4*)wb, wb1 = *(const float4*)(wb + 4);
        float v = acc[0] * wa0.x + acc[1] * wa0.y + acc[2] * wa0.z + acc[3] * wa0.w
                + acc[4] * wa1.x + acc[5] * wa1.y + acc[6] * wa1.z + acc[7] * wa1.w
                + r[0] * wb0.x + r[1] * wb0.y + r[2] * wb0.z + r[3] * wb0.w
                + r[4] * wb1.x + r[5] * wb1.y + r[6] * wb1.z + r[7] * wb1.w;
#pragma unroll
        for (int off = 32; off; off >>= 1) v += __shfl_xor(v, off);
        p[c] = v;
    }
    if (l == 0) {
#pragma unroll
        for (int c = 0; c < C; ++c) out[(size_t)node * C + c] = p[c] + bout[c];
    }
}

extern "C" void kernel_launch(void* const* d_in, const int* in_sizes, int n_in,
                              void* d_out, int out_size, void* d_ws, size_t ws_size,
                              hipStream_t stream) {
    const float* x      = (const float*)d_in[0];
    const int*   src1   = (const int*)d_in[1];
    const int*   dst1   = (const int*)d_in[2];
    const int*   src2   = (const int*)d_in[3];
    const int*   dst2   = (const int*)d_in[4];
    const float* Wrel1  = (const float*)d_in[5];
    const float* brel1  = (const float*)d_in[6];
    const float* Wroot1 = (const float*)d_in[7];
    const float* Wrel2  = (const float*)d_in[8];
    const float* brel2  = (const float*)d_in[9];
    const float* Wroot2 = (const float*)d_in[10];
    const float* Wlin   = (const float*)d_in[11];
    const float* blin   = (const float*)d_in[12];
    const float* Whead  = (const float*)d_in[13];
    const float* bhead  = (const float*)d_in[14];
    float* out = (float*)d_out;

    const int E1 = in_sizes[1];
    const int E2 = in_sizes[3];

    // ---- workspace layout (~160 MB; ws is ~800 MB per fill evidence) ----
    char* w = (char*)d_ws;
    auto alloc = [&](size_t bytes) { char* p = w; w += (bytes + 255) & ~(size_t)255; return p; };
    unsigned short* xb    = (unsigned short*)alloc((size_t)N0 * HH * 2);
    unsigned short* agg1b = (unsigned short*)alloc((size_t)M1PAD * HH * 2);
    unsigned short* hb    = (unsigned short*)alloc((size_t)M1PAD * HH * 2);
    unsigned short* Wt    = (unsigned short*)alloc((size_t)2 * HH * HH * 2);
    float* P1    = (float*)alloc((size_t)HH * C * 4);
    float* W2aT  = (float*)alloc((size_t)HH * C * 4);
    float* W2bT  = (float*)alloc((size_t)HH * C * 4);
    float* boutp = (float*)alloc(256);
    int* cnt1  = (int*)alloc((size_t)(N1 + N2) * 4);   // cnt1 | cnt2 contiguous
    int* cnt2  = cnt1 + N1;
    int* eidx1 = (int*)alloc((size_t)N1 * SLOT * 4);
    int* eidx2 = (int*)alloc((size_t)N2 * SLOT * 4);

    const short* Wrel1t  = (const short*)(Wt);
    const short* Wroot1t = (const short*)(Wt + (size_t)HH * HH);

    hipMemsetAsync(cnt1, 0, (size_t)(N1 + N2) * sizeof(int), stream);

    // ---- prep1: P1 + castw + fused [castx + count&place] ----
    const int nbCast = N0 * HH / 16 / 256;   // 12500 (16 elem/thread)
    const int epb    = (E1 + E2 + nbCast - 1) / nbCast;   // ~48 edges per cast block
    prep1_k<<<20 + 512 + nbCast, 256, 0, stream>>>(
        src1, dst1, src2, dst2, cnt1, cnt2, eidx1, eidx2, E1, E2,
        x, xb, Wrel1, Wroot1, Wt, Wlin, Whead, P1, epb);

    // ---- prep2: W2aT/W2bT + bout ----
    prep2_k<<<11, 1024, 0, stream>>>(Wrel2, Wroot2, P1,
                                     brel2, blin, Whead, bhead, W2aT, W2bT, boutp);

    // ---- layer 1 ----
    agg_bf16_k<<<(N1 + 3) / 4, 256, 0, stream>>>(xb, cnt1, eidx1, agg1b, N1);
    {
        dim3 grid(HH / 128, M1PAD / 128);
        gemm_mfma_k<<<grid, 256, 0, stream>>>(
            (const short*)agg1b, Wrel1t, (const short*)xb, Wroot1t, brel1, hb, N1);
    }

    // ---- fused layer 2 + head ----
    tail_k<<<(N2 + 3) / 4, 256, 0, stream>>>(hb, cnt2, eidx2, W2aT, W2bT, boutp, out);
}